// Round 4
// baseline (49.803 us; speedup 1.0000x reference)
//
#include <hip/hip_runtime.h>
#include <math.h>

#define F 1024
#define D 64
#define H 128

// Prep: A[i][k] = sum_r node[i][r]*W1[r][k] + b1[k]
//       Bt[k][i] = sum_r node[i][r]*W1[64+r][k]   (transposed for coalesced hot-loop reads)
__global__ __launch_bounds__(128) void prep_kernel(
    const float* __restrict__ node, const float* __restrict__ W1,
    const float* __restrict__ b1,
    float* __restrict__ A, float* __restrict__ Bt) {
  const int i = blockIdx.x;
  const int k = threadIdx.x;  // 0..127
  __shared__ float n[D];
  if (k < D) n[k] = node[i * D + k];
  __syncthreads();
  float a = b1[k];
  float b = 0.f;
#pragma unroll
  for (int r = 0; r < D; ++r) {
    const float nv = n[r];
    a = fmaf(nv, W1[r * H + k], a);
    b = fmaf(nv, W1[(D + r) * H + k], b);
  }
  A[i * H + k] = a;
  Bt[k * F + i] = b;
}

// Pair kernel: block = one output row i (512 threads, 8 waves); thread owns
// j = 2*tid, 2*tid+1 (float2 loads).  Full occupancy: 4 blocks/CU x 8 waves
// = 32 waves/CU at VGPR<=64.
// gelu_tanh(x) = x * rcp(1 + exp2(x * (C1 + C2*x^2)))
// C1 = -2*sqrt(2/pi)*log2(e), C2 = C1*0.044715.
// logits[i,j] = sum_k w2[k] * gelu(A[i,k] + Bt[k,j]); b2 cancels in softmax.
#define C1 (-2.3022082f)
#define C2 (-0.10294323f)

__global__ __launch_bounds__(512) void pair_kernel(
    const float* __restrict__ A, const float* __restrict__ Bt,
    const float* __restrict__ w2, float* __restrict__ out) {
  const int i = blockIdx.x;
  const int tid = threadIdx.x;

  __shared__ float2 sAW[H];  // (A[i][k], w2[k])
  __shared__ float redm[8];
  __shared__ float reds[8];

  if (tid < H) sAW[tid] = make_float2(A[i * H + tid], w2[tid]);
  __syncthreads();

  float acc0 = 0.f, acc1 = 0.f;

  const float2* bp = reinterpret_cast<const float2*>(Bt) + tid;  // Bt[k][2*tid..]
#pragma unroll 8
  for (int k = 0; k < H; ++k) {
    const float2 b2v = bp[k * (F / 2)];
    const float2 aw = sAW[k];
    {
      const float x = aw.x + b2v.x;
      const float arg = x * fmaf(C2, x * x, C1);
      const float r = __builtin_amdgcn_rcpf(1.f + __builtin_amdgcn_exp2f(arg));
      acc0 = fmaf(aw.y * x, r, acc0);
    }
    {
      const float x = aw.x + b2v.y;
      const float arg = x * fmaf(C2, x * x, C1);
      const float r = __builtin_amdgcn_rcpf(1.f + __builtin_amdgcn_exp2f(arg));
      acc1 = fmaf(aw.y * x, r, acc1);
    }
  }

  // ---- fused softmax over the row (1024 logits, 8 waves) ----
  const int wave = tid >> 6;
  const int lane = tid & 63;

  float m = fmaxf(acc0, acc1);
#pragma unroll
  for (int off = 32; off >= 1; off >>= 1)
    m = fmaxf(m, __shfl_xor(m, off, 64));
  if (lane == 0) redm[wave] = m;
  __syncthreads();
#pragma unroll
  for (int w = 0; w < 8; ++w) m = fmaxf(m, redm[w]);

  acc0 = __expf(acc0 - m);
  acc1 = __expf(acc1 - m);
  float s = acc0 + acc1;
#pragma unroll
  for (int off = 32; off >= 1; off >>= 1)
    s += __shfl_xor(s, off, 64);
  if (lane == 0) reds[wave] = s;
  __syncthreads();
  s = 0.f;
#pragma unroll
  for (int w = 0; w < 8; ++w) s += reds[w];

  const float inv = __builtin_amdgcn_rcpf(s);
  float2 o;
  o.x = acc0 * inv;
  o.y = acc1 * inv;
  *reinterpret_cast<float2*>(out + (size_t)i * F + 2 * tid) = o;
}

extern "C" void kernel_launch(void* const* d_in, const int* in_sizes, int n_in,
                              void* d_out, int out_size, void* d_ws, size_t ws_size,
                              hipStream_t stream) {
  const float* node = (const float*)d_in[0];  // [1024,64]
  const float* W1   = (const float*)d_in[1];  // [128,128]
  const float* b1   = (const float*)d_in[2];  // [128]
  const float* w2   = (const float*)d_in[3];  // [128]
  // d_in[4] = b2 : cancels in softmax, unused
  float* out = (float*)d_out;                 // [1024,1024]

  float* A  = (float*)d_ws;                   // [1024][128] = 512 KB
  float* Bt = A + (size_t)F * H;              // [128][1024] = 512 KB

  prep_kernel<<<F, H, 0, stream>>>(node, W1, b1, A, Bt);
  pair_kernel<<<F, 512, 0, stream>>>(A, Bt, w2, out);
}

// Round 5
// 49.746 us; speedup vs baseline: 1.0011x; 1.0011x over previous
//
#include <hip/hip_runtime.h>
#include <math.h>

#define F 1024
#define D 64
#define H 128

// Prep: A[i][k] = sum_r node[i][r]*W1[r][k] + b1[k]
//       Bt[k][i] = sum_r node[i][r]*W1[64+r][k]   (transposed for coalesced hot-loop reads)
__global__ __launch_bounds__(128) void prep_kernel(
    const float* __restrict__ node, const float* __restrict__ W1,
    const float* __restrict__ b1,
    float* __restrict__ A, float* __restrict__ Bt) {
  const int i = blockIdx.x;
  const int k = threadIdx.x;  // 0..127
  __shared__ float n[D];
  if (k < D) n[k] = node[i * D + k];
  __syncthreads();
  float a = b1[k];
  float b = 0.f;
#pragma unroll
  for (int r = 0; r < D; ++r) {
    const float nv = n[r];
    a = fmaf(nv, W1[r * H + k], a);
    b = fmaf(nv, W1[(D + r) * H + k], b);
  }
  A[i * H + k] = a;
  Bt[k * F + i] = b;
}

// Pair kernel: block = 2 output rows (i0, i0+1), 512 threads (8 waves);
// thread owns j = 2*tid, 2*tid+1 -> 4 independent gelu chains/thread
// (16 chains/SIMD at 4 waves/SIMD) and each Bt load feeds 2 rows.
// gelu_tanh(x) = x * rcp(1 + exp2(x * (C1 + C2*x^2)))
// C1 = -2*sqrt(2/pi)*log2(e), C2 = C1*0.044715.
// logits[i,j] = sum_k w2[k] * gelu(A[i,k] + Bt[k,j]); b2 cancels in softmax.
#define C1 (-2.3022082f)
#define C2 (-0.10294323f)

__device__ __forceinline__ void gelu_acc(float a, float b, float wk, float& acc) {
  const float x = a + b;
  const float arg = x * fmaf(C2, x * x, C1);
  const float r = __builtin_amdgcn_rcpf(1.f + __builtin_amdgcn_exp2f(arg));
  acc = fmaf(wk * x, r, acc);
}

__global__ __launch_bounds__(512) void pair_kernel(
    const float* __restrict__ A, const float* __restrict__ Bt,
    const float* __restrict__ w2, float* __restrict__ out) {
  const int i0 = blockIdx.x * 2;
  const int tid = threadIdx.x;

  __shared__ float4 sAW[H];  // (A[i0][k], A[i0+1][k], w2[k], 0)
  __shared__ float redm[8][2];
  __shared__ float reds[8][2];

  if (tid < H)
    sAW[tid] = make_float4(A[i0 * H + tid], A[(i0 + 1) * H + tid], w2[tid], 0.f);
  __syncthreads();

  float acc00 = 0.f, acc01 = 0.f;  // row i0,   j = 2tid, 2tid+1
  float acc10 = 0.f, acc11 = 0.f;  // row i0+1, j = 2tid, 2tid+1

  const float2* bp = reinterpret_cast<const float2*>(Bt) + tid;  // Bt[k][2*tid..]
#pragma unroll 4
  for (int k = 0; k < H; ++k) {
    const float2 b = bp[k * (F / 2)];
    const float4 aw = sAW[k];
    gelu_acc(aw.x, b.x, aw.z, acc00);
    gelu_acc(aw.x, b.y, aw.z, acc01);
    gelu_acc(aw.y, b.x, aw.z, acc10);
    gelu_acc(aw.y, b.y, aw.z, acc11);
  }

  // ---- fused softmax per row (1024 logits each, 8 waves) ----
  const int wave = tid >> 6;
  const int lane = tid & 63;

  float m0 = fmaxf(acc00, acc01);
  float m1 = fmaxf(acc10, acc11);
#pragma unroll
  for (int off = 32; off >= 1; off >>= 1) {
    m0 = fmaxf(m0, __shfl_xor(m0, off, 64));
    m1 = fmaxf(m1, __shfl_xor(m1, off, 64));
  }
  if (lane == 0) {
    redm[wave][0] = m0;
    redm[wave][1] = m1;
  }
  __syncthreads();
  m0 = redm[0][0];
  m1 = redm[0][1];
#pragma unroll
  for (int w = 1; w < 8; ++w) {
    m0 = fmaxf(m0, redm[w][0]);
    m1 = fmaxf(m1, redm[w][1]);
  }

  acc00 = __expf(acc00 - m0);
  acc01 = __expf(acc01 - m0);
  acc10 = __expf(acc10 - m1);
  acc11 = __expf(acc11 - m1);
  float s0 = acc00 + acc01;
  float s1 = acc10 + acc11;
#pragma unroll
  for (int off = 32; off >= 1; off >>= 1) {
    s0 += __shfl_xor(s0, off, 64);
    s1 += __shfl_xor(s1, off, 64);
  }
  if (lane == 0) {
    reds[wave][0] = s0;
    reds[wave][1] = s1;
  }
  __syncthreads();
  s0 = 0.f;
  s1 = 0.f;
#pragma unroll
  for (int w = 0; w < 8; ++w) {
    s0 += reds[w][0];
    s1 += reds[w][1];
  }

  const float inv0 = __builtin_amdgcn_rcpf(s0);
  const float inv1 = __builtin_amdgcn_rcpf(s1);
  float2 o0, o1;
  o0.x = acc00 * inv0;
  o0.y = acc01 * inv0;
  o1.x = acc10 * inv1;
  o1.y = acc11 * inv1;
  *reinterpret_cast<float2*>(out + (size_t)i0 * F + 2 * tid) = o0;
  *reinterpret_cast<float2*>(out + (size_t)(i0 + 1) * F + 2 * tid) = o1;
}

extern "C" void kernel_launch(void* const* d_in, const int* in_sizes, int n_in,
                              void* d_out, int out_size, void* d_ws, size_t ws_size,
                              hipStream_t stream) {
  const float* node = (const float*)d_in[0];  // [1024,64]
  const float* W1   = (const float*)d_in[1];  // [128,128]
  const float* b1   = (const float*)d_in[2];  // [128]
  const float* w2   = (const float*)d_in[3];  // [128]
  // d_in[4] = b2 : cancels in softmax, unused
  float* out = (float*)d_out;                 // [1024,1024]

  float* A  = (float*)d_ws;                   // [1024][128] = 512 KB
  float* Bt = A + (size_t)F * H;              // [128][1024] = 512 KB

  prep_kernel<<<F, H, 0, stream>>>(node, W1, b1, A, Bt);
  pair_kernel<<<F / 2, 512, 0, stream>>>(A, Bt, w2, out);
}

// Round 6
// 44.339 us; speedup vs baseline: 1.1232x; 1.1219x over previous
//
#include <hip/hip_runtime.h>
#include <math.h>

#define F 1024
#define D 64
#define H 128

typedef float v2f __attribute__((ext_vector_type(2)));

// Prep: A[i][k] = sum_r node[i][r]*W1[r][k] + b1[k]
//       Bt[k][i] = sum_r node[i][r]*W1[64+r][k]   (transposed for coalesced hot-loop reads)
__global__ __launch_bounds__(128) void prep_kernel(
    const float* __restrict__ node, const float* __restrict__ W1,
    const float* __restrict__ b1,
    float* __restrict__ A, float* __restrict__ Bt) {
  const int i = blockIdx.x;
  const int k = threadIdx.x;  // 0..127
  __shared__ float n[D];
  if (k < D) n[k] = node[i * D + k];
  __syncthreads();
  float a = b1[k];
  float b = 0.f;
#pragma unroll
  for (int r = 0; r < D; ++r) {
    const float nv = n[r];
    a = fmaf(nv, W1[r * H + k], a);
    b = fmaf(nv, W1[(D + r) * H + k], b);
  }
  A[i * H + k] = a;
  Bt[k * F + i] = b;
}

// Pair kernel: block = 2 output rows (i0, i0+1), 512 threads (8 waves);
// thread owns j = 2*tid, 2*tid+1, PACKED as one float2 lane pair so the
// 7 full-rate VALU ops/element become v_pk_* (2 f32/instr on gfx950).
// gelu_tanh(x) = x * rcp(1 + exp2(x * (C1 + C2*x^2)))
// C1 = -2*sqrt(2/pi)*log2(e), C2 = C1*0.044715.
// logits[i,j] = sum_k w2[k] * gelu(A[i,k] + Bt[k,j]); b2 cancels in softmax.
#define C1 (-2.3022082f)
#define C2 (-0.10294323f)

__device__ __forceinline__ void gelu_acc_pk(float a, v2f b, float wk, v2f& acc) {
  const v2f X = a + b;                                   // v_pk_add (splat)
  const v2f U = X * X;                                   // v_pk_mul
  const v2f P = __builtin_elementwise_fma((v2f)(C2), U, (v2f)(C1));  // v_pk_fma
  const v2f Arg = X * P;                                 // v_pk_mul
  v2f E;
  E.x = __builtin_amdgcn_exp2f(Arg.x);                   // v_exp_f32
  E.y = __builtin_amdgcn_exp2f(Arg.y);                   // v_exp_f32
  const v2f Dn = 1.0f + E;                               // v_pk_add
  v2f R;
  R.x = __builtin_amdgcn_rcpf(Dn.x);                     // v_rcp_f32
  R.y = __builtin_amdgcn_rcpf(Dn.y);                     // v_rcp_f32
  const v2f WX = wk * X;                                 // v_pk_mul (splat)
  acc = __builtin_elementwise_fma(WX, R, acc);           // v_pk_fma
}

__global__ __launch_bounds__(512) void pair_kernel(
    const float* __restrict__ A, const float* __restrict__ Bt,
    const float* __restrict__ w2, float* __restrict__ out) {
  const int i0 = blockIdx.x * 2;
  const int tid = threadIdx.x;

  __shared__ float4 sAW[H];  // (A[i0][k], A[i0+1][k], w2[k], 0)
  __shared__ float redm[8][2];
  __shared__ float reds[8][2];

  if (tid < H)
    sAW[tid] = make_float4(A[i0 * H + tid], A[(i0 + 1) * H + tid], w2[tid], 0.f);
  __syncthreads();

  v2f acc0 = {0.f, 0.f};  // row i0,   j = 2tid, 2tid+1
  v2f acc1 = {0.f, 0.f};  // row i0+1, j = 2tid, 2tid+1

  const v2f* bp = reinterpret_cast<const v2f*>(Bt) + tid;  // Bt[k][2*tid..]
#pragma unroll 8
  for (int k = 0; k < H; ++k) {
    const v2f b = *bp;
    bp += F / 2;
    const float4 aw = sAW[k];
    gelu_acc_pk(aw.x, b, aw.z, acc0);
    gelu_acc_pk(aw.y, b, aw.z, acc1);
  }

  // ---- fused softmax per row (1024 logits each, 8 waves) ----
  const int wave = tid >> 6;
  const int lane = tid & 63;

  float m0 = fmaxf(acc0.x, acc0.y);
  float m1 = fmaxf(acc1.x, acc1.y);
#pragma unroll
  for (int off = 32; off >= 1; off >>= 1) {
    m0 = fmaxf(m0, __shfl_xor(m0, off, 64));
    m1 = fmaxf(m1, __shfl_xor(m1, off, 64));
  }
  if (lane == 0) {
    redm[wave][0] = m0;
    redm[wave][1] = m1;
  }
  __syncthreads();
  m0 = redm[0][0];
  m1 = redm[0][1];
#pragma unroll
  for (int w = 1; w < 8; ++w) {
    m0 = fmaxf(m0, redm[w][0]);
    m1 = fmaxf(m1, redm[w][1]);
  }

  float e00 = __expf(acc0.x - m0);
  float e01 = __expf(acc0.y - m0);
  float e10 = __expf(acc1.x - m1);
  float e11 = __expf(acc1.y - m1);
  float s0 = e00 + e01;
  float s1 = e10 + e11;
#pragma unroll
  for (int off = 32; off >= 1; off >>= 1) {
    s0 += __shfl_xor(s0, off, 64);
    s1 += __shfl_xor(s1, off, 64);
  }
  if (lane == 0) {
    reds[wave][0] = s0;
    reds[wave][1] = s1;
  }
  __syncthreads();
  s0 = 0.f;
  s1 = 0.f;
#pragma unroll
  for (int w = 0; w < 8; ++w) {
    s0 += reds[w][0];
    s1 += reds[w][1];
  }

  const float inv0 = __builtin_amdgcn_rcpf(s0);
  const float inv1 = __builtin_amdgcn_rcpf(s1);
  float2 o0, o1;
  o0.x = e00 * inv0;
  o0.y = e01 * inv0;
  o1.x = e10 * inv1;
  o1.y = e11 * inv1;
  *reinterpret_cast<float2*>(out + (size_t)i0 * F + 2 * tid) = o0;
  *reinterpret_cast<float2*>(out + (size_t)(i0 + 1) * F + 2 * tid) = o1;
}

extern "C" void kernel_launch(void* const* d_in, const int* in_sizes, int n_in,
                              void* d_out, int out_size, void* d_ws, size_t ws_size,
                              hipStream_t stream) {
  const float* node = (const float*)d_in[0];  // [1024,64]
  const float* W1   = (const float*)d_in[1];  // [128,128]
  const float* b1   = (const float*)d_in[2];  // [128]
  const float* w2   = (const float*)d_in[3];  // [128]
  // d_in[4] = b2 : cancels in softmax, unused
  float* out = (float*)d_out;                 // [1024,1024]

  float* A  = (float*)d_ws;                   // [1024][128] = 512 KB
  float* Bt = A + (size_t)F * H;              // [128][1024] = 512 KB

  prep_kernel<<<F, H, 0, stream>>>(node, W1, b1, A, Bt);
  pair_kernel<<<F / 2, 512, 0, stream>>>(A, Bt, w2, out);
}